// Round 2
// baseline (293.198 us; speedup 1.0000x reference)
//
#include <hip/hip_runtime.h>
#include <stdint.h>

#define N_NODES 10000
#define N_EDGES 160000
#define DIM     512
#define N_ELEMS 5120000   // N_NODES*DIM
#define NEG_SLOPE 0.25f

// ---------------- threefry2x32-20, key = jax.random.key(42) = (0, 42) ----------------
// Verified against Random123 KAT: key=(0,0), ctr=(0,0) -> (0x6b200159, 0x99ba4efe).
__device__ __forceinline__ uint32_t rotl32(uint32_t x, uint32_t d) {
    return (x << d) | (x >> (32u - d));
}

__device__ __forceinline__ void threefry_42(uint32_t x0, uint32_t x1,
                                            uint32_t& o0, uint32_t& o1) {
    const uint32_t ks0 = 0u, ks1 = 42u, ks2 = 0x1BD11BDAu ^ 42u;
    x0 += ks0; x1 += ks1;
#define TF_R4(a,b,c,d) \
    x0 += x1; x1 = rotl32(x1,a); x1 ^= x0; \
    x0 += x1; x1 = rotl32(x1,b); x1 ^= x0; \
    x0 += x1; x1 = rotl32(x1,c); x1 ^= x0; \
    x0 += x1; x1 = rotl32(x1,d); x1 ^= x0;
    TF_R4(13,15,26,6);  x0 += ks1; x1 += ks2 + 1u;
    TF_R4(17,29,16,24); x0 += ks2; x1 += ks0 + 2u;
    TF_R4(13,15,26,6);  x0 += ks0; x1 += ks1 + 3u;
    TF_R4(17,29,16,24); x0 += ks1; x1 += ks2 + 4u;
    TF_R4(13,15,26,6);  x0 += ks2; x1 += ks0 + 5u;
#undef TF_R4
    o0 = x0; o1 = x1;
}

// ---------------- CSR build ----------------
__global__ void hist_kernel(const int* __restrict__ rows, int* __restrict__ cnt) {
    int e = blockIdx.x * blockDim.x + threadIdx.x;
    if (e < N_EDGES) atomicAdd(&cnt[rows[e]], 1);
}

__global__ __launch_bounds__(1024)
void scan_kernel(const int* __restrict__ cnt, int* __restrict__ rs, int* __restrict__ cur) {
    __shared__ int s[1024];
    int t = threadIdx.x;
    int base_i = t * 10;
    int local[10];
    int p = 0;
    if (t < 1000) {
        #pragma unroll
        for (int j = 0; j < 10; ++j) { local[j] = cnt[base_i + j]; p += local[j]; }
    }
    s[t] = p;
    __syncthreads();
    for (int off = 1; off < 1024; off <<= 1) {
        int v = (t >= off) ? s[t - off] : 0;
        __syncthreads();
        s[t] += v;
        __syncthreads();
    }
    if (t < 1000) {
        int run = s[t] - p;  // exclusive prefix
        #pragma unroll
        for (int j = 0; j < 10; ++j) {
            rs[base_i + j]  = run;
            cur[base_i + j] = run;
            run += local[j];
        }
        if (t == 999) rs[N_NODES] = run;
    }
}

__global__ void scatter_kernel(const int* __restrict__ rows, const int* __restrict__ cols,
                               const float* __restrict__ vals, int* __restrict__ cur,
                               int* __restrict__ scol, float* __restrict__ sval) {
    int e = blockIdx.x * blockDim.x + threadIdx.x;
    if (e < N_EDGES) {
        int r = rows[e];
        int p = atomicAdd(&cur[r], 1);
        scol[p] = cols[e];
        sval[p] = vals[e];
    }
}

// ---------------- fp32 tiled GEMM: C[M,512] = A[M,512] @ B[512,512] ----------------
#define BM 64
#define BN 64
#define BK 16
#define LDT 68   // padded LDS pitch (floats); 68*4=272B is 16B-aligned per row

__global__ __launch_bounds__(256)
void gemm_kernel(const float* __restrict__ A, const float* __restrict__ B,
                 float* __restrict__ C, int M) {
    __shared__ float As[BK][LDT];
    __shared__ float Bs[BK][LDT];
    int tid = threadIdx.x;
    int bm = blockIdx.x * BM;
    int bn = blockIdx.y * BN;
    int tx = tid & 15, ty = tid >> 4;
    int am = tid >> 2, ak = (tid & 3) * 4;     // A tile load coords
    int bk = tid >> 4, bn4 = (tid & 15) * 4;   // B tile load coords
    const bool arow_ok = (bm + am) < M;

    float acc[4][4] = {};

    for (int k0 = 0; k0 < DIM; k0 += BK) {
        float4 a4 = make_float4(0.f, 0.f, 0.f, 0.f);
        if (arow_ok) a4 = *(const float4*)&A[(size_t)(bm + am) * DIM + k0 + ak];
        float4 b4 = *(const float4*)&B[(size_t)(k0 + bk) * DIM + bn + bn4];
        __syncthreads();
        As[ak + 0][am] = a4.x;
        As[ak + 1][am] = a4.y;
        As[ak + 2][am] = a4.z;
        As[ak + 3][am] = a4.w;
        *(float4*)&Bs[bk][bn4] = b4;
        __syncthreads();
        #pragma unroll
        for (int k = 0; k < BK; ++k) {
            float4 a = *(const float4*)&As[k][ty * 4];
            float4 b = *(const float4*)&Bs[k][tx * 4];
            acc[0][0] = fmaf(a.x, b.x, acc[0][0]);
            acc[0][1] = fmaf(a.x, b.y, acc[0][1]);
            acc[0][2] = fmaf(a.x, b.z, acc[0][2]);
            acc[0][3] = fmaf(a.x, b.w, acc[0][3]);
            acc[1][0] = fmaf(a.y, b.x, acc[1][0]);
            acc[1][1] = fmaf(a.y, b.y, acc[1][1]);
            acc[1][2] = fmaf(a.y, b.z, acc[1][2]);
            acc[1][3] = fmaf(a.y, b.w, acc[1][3]);
            acc[2][0] = fmaf(a.z, b.x, acc[2][0]);
            acc[2][1] = fmaf(a.z, b.y, acc[2][1]);
            acc[2][2] = fmaf(a.z, b.z, acc[2][2]);
            acc[2][3] = fmaf(a.z, b.w, acc[2][3]);
            acc[3][0] = fmaf(a.w, b.x, acc[3][0]);
            acc[3][1] = fmaf(a.w, b.y, acc[3][1]);
            acc[3][2] = fmaf(a.w, b.z, acc[3][2]);
            acc[3][3] = fmaf(a.w, b.w, acc[3][3]);
        }
    }
    #pragma unroll
    for (int i = 0; i < 4; ++i) {
        int row = bm + ty * 4 + i;
        if (row < M) {
            float4 o = make_float4(acc[i][0], acc[i][1], acc[i][2], acc[i][3]);
            *(float4*)&C[(size_t)row * DIM + bn + tx * 4] = o;
        }
    }
}

// ---------------- SpMM (CSR rows) + bias + leaky_relu ----------------
__global__ __launch_bounds__(128)
void spmm_kernel(const float* __restrict__ X, const int* __restrict__ rs,
                 const int* __restrict__ scol, const float* __restrict__ sval,
                 const float* __restrict__ bias, float* __restrict__ out) {
    int row = blockIdx.x;
    int tid = threadIdx.x;                      // 0..127, each owns a float4 of DIM
    int start = rs[row], end = rs[row + 1];
    const float4* X4 = (const float4*)X;
    float4 acc  = make_float4(0.f, 0.f, 0.f, 0.f);
    float4 acc2 = make_float4(0.f, 0.f, 0.f, 0.f);
    int p = start;
    for (; p + 1 < end; p += 2) {
        int   c0 = scol[p],     c1 = scol[p + 1];
        float v0 = sval[p],     v1 = sval[p + 1];
        float4 x0 = X4[(size_t)c0 * 128 + tid];
        float4 x1 = X4[(size_t)c1 * 128 + tid];
        acc.x  = fmaf(v0, x0.x, acc.x);  acc.y  = fmaf(v0, x0.y, acc.y);
        acc.z  = fmaf(v0, x0.z, acc.z);  acc.w  = fmaf(v0, x0.w, acc.w);
        acc2.x = fmaf(v1, x1.x, acc2.x); acc2.y = fmaf(v1, x1.y, acc2.y);
        acc2.z = fmaf(v1, x1.z, acc2.z); acc2.w = fmaf(v1, x1.w, acc2.w);
    }
    if (p < end) {
        int c0 = scol[p]; float v0 = sval[p];
        float4 x0 = X4[(size_t)c0 * 128 + tid];
        acc.x = fmaf(v0, x0.x, acc.x);  acc.y = fmaf(v0, x0.y, acc.y);
        acc.z = fmaf(v0, x0.z, acc.z);  acc.w = fmaf(v0, x0.w, acc.w);
    }
    acc.x += acc2.x; acc.y += acc2.y; acc.z += acc2.z; acc.w += acc2.w;
    float4 b = ((const float4*)bias)[tid];
    float4 r;
    r.x = acc.x + b.x; r.y = acc.y + b.y; r.z = acc.z + b.z; r.w = acc.w + b.w;
    r.x = (r.x >= 0.f) ? r.x : NEG_SLOPE * r.x;
    r.y = (r.y >= 0.f) ? r.y : NEG_SLOPE * r.y;
    r.z = (r.z >= 0.f) ? r.z : NEG_SLOPE * r.z;
    r.w = (r.w >= 0.f) ? r.w : NEG_SLOPE * r.w;
    ((float4*)out)[(size_t)row * 128 + tid] = r;
}

// ---------------- dropout: JAX partitionable threefry, key=42, p_keep=0.5 ----------------
// counts = iota(uint64, 5.12e6); per element i: (b1,b2) = threefry(key, hi=0, lo=i);
// 32-bit bits = b1 ^ b2; uniform = bitcast(bits>>9 | 0x3f800000)-1; keep iff u<0.5
// iff MSB(bits)==0. Kept elements scaled by 1/(1-p)=2.
__global__ void dropout_kernel(float* __restrict__ h) {
    int i = blockIdx.x * blockDim.x + threadIdx.x;
    if (i >= N_ELEMS) return;
    uint32_t b1, b2;
    threefry_42(0u, (uint32_t)i, b1, b2);
    uint32_t bits = b1 ^ b2;
    float v = h[i];
    h[i] = ((int)bits >= 0) ? v * 2.0f : 0.0f;
}

// ---------------- launch ----------------
extern "C" void kernel_launch(void* const* d_in, const int* in_sizes, int n_in,
                              void* d_out, int out_size, void* d_ws, size_t ws_size,
                              hipStream_t stream) {
    const float* H    = (const float*)d_in[0];
    const int*   rows = (const int*)  d_in[1];
    const int*   cols = (const int*)  d_in[2];
    const float* vals = (const float*)d_in[3];
    const float* W1   = (const float*)d_in[4];
    const float* b1   = (const float*)d_in[5];
    const float* W2   = (const float*)d_in[6];
    const float* b2   = (const float*)d_in[7];
    float* out = (float*)d_out;

    // ws layout: small CSR arrays first, then one dense buffer (~22 MB total).
    char* ws = (char*)d_ws;
    size_t off = 0;
    auto alloc = [&](size_t bytes) -> void* {
        off = (off + 255) & ~(size_t)255;
        void* p = ws + off;
        off += bytes;
        return p;
    };
    int*   cnt  = (int*)  alloc((size_t)N_NODES * 4);
    int*   rs   = (int*)  alloc((size_t)(N_NODES + 1) * 4);
    int*   cur  = (int*)  alloc((size_t)N_NODES * 4);
    int*   scol = (int*)  alloc((size_t)N_EDGES * 4);
    float* sval = (float*)alloc((size_t)N_EDGES * 4);
    float* X    = (float*)alloc((size_t)N_ELEMS * 4);   // GEMM output (both layers)
    float* h    = out;                                   // layer-1 hidden lives in d_out

    // CSR build
    hipMemsetAsync(cnt, 0, (size_t)N_NODES * 4, stream);
    hist_kernel<<<(N_EDGES + 255) / 256, 256, 0, stream>>>(rows, cnt);
    scan_kernel<<<1, 1024, 0, stream>>>(cnt, rs, cur);
    scatter_kernel<<<(N_EDGES + 255) / 256, 256, 0, stream>>>(rows, cols, vals, cur, scol, sval);

    dim3 gemm_grid((N_NODES + BM - 1) / BM, DIM / BN);
    // layer 1: X = H@W1 ; h = leaky(A@X + b1) ; h = dropout(h)
    gemm_kernel<<<gemm_grid, 256, 0, stream>>>(H, W1, X, N_NODES);
    spmm_kernel<<<N_NODES, 128, 0, stream>>>(X, rs, scol, sval, b1, h);
    dropout_kernel<<<(N_ELEMS + 255) / 256, 256, 0, stream>>>(h);
    // layer 2: X = h@W2 ; out = leaky(A@X + b2)
    gemm_kernel<<<gemm_grid, 256, 0, stream>>>(h, W2, X, N_NODES);
    spmm_kernel<<<N_NODES, 128, 0, stream>>>(X, rs, scol, sval, b2, out);
}

// Round 3
// 126.927 us; speedup vs baseline: 2.3100x; 2.3100x over previous
//
#include <hip/hip_runtime.h>
#include <stdint.h>

#define N_NODES 10000
#define M_PAD   10112    // padded row count (multiple of 128) for MFMA staging
#define N_EDGES 160000
#define DIM     512
#define N_ELEMS 5120000  // N_NODES*DIM
#define NEG_SLOPE 0.25f

typedef short     short8 __attribute__((ext_vector_type(8)));
typedef __bf16    bf16x8 __attribute__((ext_vector_type(8)));
typedef float     f32x4  __attribute__((ext_vector_type(4)));

__device__ __forceinline__ unsigned short f2bf(float f) {   // RNE f32->bf16
    uint32_t u = __builtin_bit_cast(uint32_t, f);
    uint32_t r = (u + 0x7fffu + ((u >> 16) & 1u)) >> 16;
    return (unsigned short)r;
}
__device__ __forceinline__ float b2f(unsigned short u) {
    return __builtin_bit_cast(float, (uint32_t)u << 16);
}

// ---------------- threefry2x32-20, key = jax.random.key(42) = (0, 42) ----------------
__device__ __forceinline__ uint32_t rotl32(uint32_t x, uint32_t d) {
    return (x << d) | (x >> (32u - d));
}
__device__ __forceinline__ void threefry_42(uint32_t x0, uint32_t x1,
                                            uint32_t& o0, uint32_t& o1) {
    const uint32_t ks0 = 0u, ks1 = 42u, ks2 = 0x1BD11BDAu ^ 42u;
    x0 += ks0; x1 += ks1;
#define TF_R4(a,b,c,d) \
    x0 += x1; x1 = rotl32(x1,a); x1 ^= x0; \
    x0 += x1; x1 = rotl32(x1,b); x1 ^= x0; \
    x0 += x1; x1 = rotl32(x1,c); x1 ^= x0; \
    x0 += x1; x1 = rotl32(x1,d); x1 ^= x0;
    TF_R4(13,15,26,6);  x0 += ks1; x1 += ks2 + 1u;
    TF_R4(17,29,16,24); x0 += ks2; x1 += ks0 + 2u;
    TF_R4(13,15,26,6);  x0 += ks0; x1 += ks1 + 3u;
    TF_R4(17,29,16,24); x0 += ks1; x1 += ks2 + 4u;
    TF_R4(13,15,26,6);  x0 += ks2; x1 += ks0 + 5u;
#undef TF_R4
    o0 = x0; o1 = x1;
}

// ---------------- CSR build ----------------
__global__ void hist_kernel(const int* __restrict__ rows, int* __restrict__ cnt) {
    int e = blockIdx.x * blockDim.x + threadIdx.x;
    if (e < N_EDGES) atomicAdd(&cnt[rows[e]], 1);
}

__global__ __launch_bounds__(1024)
void scan_kernel(const int* __restrict__ cnt, int* __restrict__ rs, int* __restrict__ cur) {
    __shared__ int s[1024];
    int t = threadIdx.x;
    int base_i = t * 10;
    int local[10];
    int p = 0;
    if (t < 1000) {
        #pragma unroll
        for (int j = 0; j < 10; ++j) { local[j] = cnt[base_i + j]; p += local[j]; }
    }
    s[t] = p;
    __syncthreads();
    for (int off = 1; off < 1024; off <<= 1) {
        int v = (t >= off) ? s[t - off] : 0;
        __syncthreads();
        s[t] += v;
        __syncthreads();
    }
    if (t < 1000) {
        int run = s[t] - p;
        #pragma unroll
        for (int j = 0; j < 10; ++j) {
            rs[base_i + j]  = run;
            cur[base_i + j] = run;
            run += local[j];
        }
        if (t == 999) rs[N_NODES] = run;
    }
}

__global__ void scatter_kernel(const int* __restrict__ rows, const int* __restrict__ cols,
                               const float* __restrict__ vals, int* __restrict__ cur,
                               int* __restrict__ scol, float* __restrict__ sval) {
    int e = blockIdx.x * blockDim.x + threadIdx.x;
    if (e < N_EDGES) {
        int r = rows[e];
        int p = atomicAdd(&cur[r], 1);
        scol[p] = cols[e];
        sval[p] = vals[e];
    }
}

// ---------------- fp32 -> bf16 convert (H -> Abf) ----------------
__global__ void convert_kernel(const float* __restrict__ src, unsigned short* __restrict__ dst) {
    int i = blockIdx.x * blockDim.x + threadIdx.x;   // one float4 per thread
    if (i * 4 >= N_ELEMS) return;
    float4 v = ((const float4*)src)[i];
    ushort4 o;
    o.x = f2bf(v.x); o.y = f2bf(v.y); o.z = f2bf(v.z); o.w = f2bf(v.w);
    ((ushort4*)dst)[i] = o;
}

// ---------------- W [K][N] fp32 -> WT [N][K] bf16 (LDS tile transpose) ----------------
__global__ __launch_bounds__(256)
void transpose_kernel(const float* __restrict__ W, unsigned short* __restrict__ WT) {
    __shared__ float t[64][65];
    int k0 = blockIdx.x * 64, n0 = blockIdx.y * 64;
    int tx = threadIdx.x & 15, ty = threadIdx.x >> 4;
    #pragma unroll
    for (int i = 0; i < 4; ++i) {
        int k = i * 16 + ty;
        float4 v = *(const float4*)&W[(size_t)(k0 + k) * DIM + n0 + tx * 4];
        t[k][tx * 4 + 0] = v.x; t[k][tx * 4 + 1] = v.y;
        t[k][tx * 4 + 2] = v.z; t[k][tx * 4 + 3] = v.w;
    }
    __syncthreads();
    #pragma unroll
    for (int i = 0; i < 4; ++i) {
        int n = i * 16 + ty;
        ushort4 o;
        o.x = f2bf(t[tx * 4 + 0][n]); o.y = f2bf(t[tx * 4 + 1][n]);
        o.z = f2bf(t[tx * 4 + 2][n]); o.w = f2bf(t[tx * 4 + 3][n]);
        *(ushort4*)&WT[(size_t)(n0 + n) * DIM + k0 + tx * 4] = o;
    }
}

// ---------------- bf16 MFMA GEMM: C[M][512] = A[M][512] @ WT[n][k]^T ----------------
// 128x128 tile, BK=64, 256 threads = 4 waves (2x2), each wave 64x64 (4x4 frags).
// LDS tiles stored as [row][8 slots of 16B], slot XOR-swizzled by (row&7):
// linear LDS dest for global_load_lds + inverse-swizzled GLOBAL source (rule #21).
__global__ __launch_bounds__(256)
void mfma_gemm(const unsigned short* __restrict__ A, const unsigned short* __restrict__ BT,
               unsigned short* __restrict__ C, int M) {
    __shared__ short8 As[1024];   // 128 rows x 8 slots
    __shared__ short8 Bs[1024];
    int tid  = threadIdx.x;
    int wid  = tid >> 6, lane = tid & 63;
    int bm   = blockIdx.x * 128;
    int bn   = blockIdx.y * 128;
    int wm   = (wid >> 1) * 64, wn = (wid & 1) * 64;

    f32x4 acc[4][4] = {};

    int srow = lane >> 3;     // row within 8-row staging chunk
    int sslot = lane & 7;

    for (int k0 = 0; k0 < DIM; k0 += 64) {
        #pragma unroll
        for (int c = 0; c < 4; ++c) {
            int chunk = wid * 4 + c;            // 16 chunks x 8 rows = 128 rows
            int r  = chunk * 8 + srow;
            int ks = sslot ^ (r & 7);           // inverse-swizzled source slot
            const unsigned short* ga = A  + (size_t)(bm + r) * DIM + k0 + ks * 8;
            const unsigned short* gb = BT + (size_t)(bn + r) * DIM + k0 + ks * 8;
            __builtin_amdgcn_global_load_lds(
                (const __attribute__((address_space(1))) void*)ga,
                (__attribute__((address_space(3))) void*)&As[chunk * 64], 16, 0, 0);
            __builtin_amdgcn_global_load_lds(
                (const __attribute__((address_space(1))) void*)gb,
                (__attribute__((address_space(3))) void*)&Bs[chunk * 64], 16, 0, 0);
        }
        __syncthreads();                         // drains vmcnt before compute

        int lrow = lane & 15;
        int kgrp = lane >> 4;                    // 0..3
        #pragma unroll
        for (int ks = 0; ks < 2; ++ks) {
            short8 af[4], bfr[4];
            #pragma unroll
            for (int i = 0; i < 4; ++i) {
                int r = wm + i * 16 + lrow;
                af[i]  = As[r * 8 + ((ks * 4 + kgrp) ^ (r & 7))];
                int n = wn + i * 16 + lrow;
                bfr[i] = Bs[n * 8 + ((ks * 4 + kgrp) ^ (n & 7))];
            }
            #pragma unroll
            for (int i = 0; i < 4; ++i)
                #pragma unroll
                for (int j = 0; j < 4; ++j)
                    acc[i][j] = __builtin_amdgcn_mfma_f32_16x16x32_bf16(
                        __builtin_bit_cast(bf16x8, af[i]),
                        __builtin_bit_cast(bf16x8, bfr[j]), acc[i][j], 0, 0, 0);
        }
        __syncthreads();
    }

    // epilogue: C/D layout col=lane&15, row=(lane>>4)*4+reg  [m89]
    int crow = (lane >> 4) * 4;
    int ccol = lane & 15;
    #pragma unroll
    for (int i = 0; i < 4; ++i) {
        #pragma unroll
        for (int r = 0; r < 4; ++r) {
            int row = bm + wm + i * 16 + crow + r;
            if (row < M) {
                size_t base = (size_t)row * DIM + bn + wn + ccol;
                #pragma unroll
                for (int j = 0; j < 4; ++j)
                    C[base + j * 16] = f2bf(acc[i][j][r]);
            }
        }
    }
}

// ---------------- SpMM layer1: h = bf16(dropout(leaky(A@X + b1))) ----------------
__global__ __launch_bounds__(128)
void spmm1_kernel(const unsigned short* __restrict__ X, const int* __restrict__ rs,
                  const int* __restrict__ scol, const float* __restrict__ sval,
                  const float* __restrict__ bias, unsigned short* __restrict__ hout) {
    int row = blockIdx.x;
    int t = threadIdx.x;                         // owns cols 4t..4t+3
    int start = rs[row], end = rs[row + 1];
    const ushort4* X4 = (const ushort4*)X;       // row stride = 128 ushort4
    float a0 = 0.f, a1 = 0.f, a2 = 0.f, a3 = 0.f;
    float c0 = 0.f, c1 = 0.f, c2 = 0.f, c3 = 0.f;
    int p = start;
    for (; p + 1 < end; p += 2) {
        int   i0 = scol[p], i1 = scol[p + 1];
        float v0 = sval[p], v1 = sval[p + 1];
        ushort4 x0 = X4[(size_t)i0 * 128 + t];
        ushort4 x1 = X4[(size_t)i1 * 128 + t];
        a0 = fmaf(v0, b2f(x0.x), a0); a1 = fmaf(v0, b2f(x0.y), a1);
        a2 = fmaf(v0, b2f(x0.z), a2); a3 = fmaf(v0, b2f(x0.w), a3);
        c0 = fmaf(v1, b2f(x1.x), c0); c1 = fmaf(v1, b2f(x1.y), c1);
        c2 = fmaf(v1, b2f(x1.z), c2); c3 = fmaf(v1, b2f(x1.w), c3);
    }
    if (p < end) {
        int i0 = scol[p]; float v0 = sval[p];
        ushort4 x0 = X4[(size_t)i0 * 128 + t];
        a0 = fmaf(v0, b2f(x0.x), a0); a1 = fmaf(v0, b2f(x0.y), a1);
        a2 = fmaf(v0, b2f(x0.z), a2); a3 = fmaf(v0, b2f(x0.w), a3);
    }
    float r[4];
    float4 b = *(const float4*)&bias[t * 4];
    r[0] = a0 + c0 + b.x; r[1] = a1 + c1 + b.y;
    r[2] = a2 + c2 + b.z; r[3] = a3 + c3 + b.w;
    uint32_t e0 = (uint32_t)row * DIM + t * 4;
    #pragma unroll
    for (int j = 0; j < 4; ++j) {
        float v = r[j];
        v = (v >= 0.f) ? v : NEG_SLOPE * v;
        uint32_t o0, o1;
        threefry_42(0u, e0 + j, o0, o1);         // partitionable: bits = o0^o1, keep iff MSB clear
        uint32_t bits = o0 ^ o1;
        r[j] = ((int)bits >= 0) ? v * 2.0f : 0.0f;
    }
    ushort4 o;
    o.x = f2bf(r[0]); o.y = f2bf(r[1]); o.z = f2bf(r[2]); o.w = f2bf(r[3]);
    ((ushort4*)hout)[(size_t)row * 128 + t] = o;
}

// ---------------- SpMM layer2: out = leaky(A@X + b2), fp32 ----------------
__global__ __launch_bounds__(128)
void spmm2_kernel(const unsigned short* __restrict__ X, const int* __restrict__ rs,
                  const int* __restrict__ scol, const float* __restrict__ sval,
                  const float* __restrict__ bias, float* __restrict__ out) {
    int row = blockIdx.x;
    int t = threadIdx.x;
    int start = rs[row], end = rs[row + 1];
    const ushort4* X4 = (const ushort4*)X;
    float a0 = 0.f, a1 = 0.f, a2 = 0.f, a3 = 0.f;
    float c0 = 0.f, c1 = 0.f, c2 = 0.f, c3 = 0.f;
    int p = start;
    for (; p + 1 < end; p += 2) {
        int   i0 = scol[p], i1 = scol[p + 1];
        float v0 = sval[p], v1 = sval[p + 1];
        ushort4 x0 = X4[(size_t)i0 * 128 + t];
        ushort4 x1 = X4[(size_t)i1 * 128 + t];
        a0 = fmaf(v0, b2f(x0.x), a0); a1 = fmaf(v0, b2f(x0.y), a1);
        a2 = fmaf(v0, b2f(x0.z), a2); a3 = fmaf(v0, b2f(x0.w), a3);
        c0 = fmaf(v1, b2f(x1.x), c0); c1 = fmaf(v1, b2f(x1.y), c1);
        c2 = fmaf(v1, b2f(x1.z), c2); c3 = fmaf(v1, b2f(x1.w), c3);
    }
    if (p < end) {
        int i0 = scol[p]; float v0 = sval[p];
        ushort4 x0 = X4[(size_t)i0 * 128 + t];
        a0 = fmaf(v0, b2f(x0.x), a0); a1 = fmaf(v0, b2f(x0.y), a1);
        a2 = fmaf(v0, b2f(x0.z), a2); a3 = fmaf(v0, b2f(x0.w), a3);
    }
    float4 b = *(const float4*)&bias[t * 4];
    float4 r;
    r.x = a0 + c0 + b.x; r.y = a1 + c1 + b.y;
    r.z = a2 + c2 + b.z; r.w = a3 + c3 + b.w;
    r.x = (r.x >= 0.f) ? r.x : NEG_SLOPE * r.x;
    r.y = (r.y >= 0.f) ? r.y : NEG_SLOPE * r.y;
    r.z = (r.z >= 0.f) ? r.z : NEG_SLOPE * r.z;
    r.w = (r.w >= 0.f) ? r.w : NEG_SLOPE * r.w;
    ((float4*)out)[(size_t)row * 128 + t] = r;
}

// ---------------- launch ----------------
extern "C" void kernel_launch(void* const* d_in, const int* in_sizes, int n_in,
                              void* d_out, int out_size, void* d_ws, size_t ws_size,
                              hipStream_t stream) {
    const float* H    = (const float*)d_in[0];
    const int*   rows = (const int*)  d_in[1];
    const int*   cols = (const int*)  d_in[2];
    const float* vals = (const float*)d_in[3];
    const float* W1   = (const float*)d_in[4];
    const float* b1   = (const float*)d_in[5];
    const float* W2   = (const float*)d_in[6];
    const float* b2   = (const float*)d_in[7];
    float* out = (float*)d_out;

    char* ws = (char*)d_ws;
    size_t off = 0;
    auto alloc = [&](size_t bytes) -> void* {
        off = (off + 255) & ~(size_t)255;
        void* p = ws + off;
        off += bytes;
        return p;
    };
    int*   cnt  = (int*)  alloc((size_t)N_NODES * 4);
    int*   rs   = (int*)  alloc((size_t)(N_NODES + 1) * 4);
    int*   cur  = (int*)  alloc((size_t)N_NODES * 4);
    int*   scol = (int*)  alloc((size_t)N_EDGES * 4);
    float* sval = (float*)alloc((size_t)N_EDGES * 4);
    unsigned short* WT1 = (unsigned short*)alloc((size_t)DIM * DIM * 2);
    unsigned short* WT2 = (unsigned short*)alloc((size_t)DIM * DIM * 2);
    unsigned short* Abf = (unsigned short*)alloc((size_t)M_PAD * DIM * 2);   // bf16 H (padded)
    unsigned short* hbf = (unsigned short*)alloc((size_t)M_PAD * DIM * 2);   // bf16 hidden (padded)
    unsigned short* Xbf = (unsigned short*)alloc((size_t)N_NODES * DIM * 2); // GEMM outputs

    // conversions + CSR build
    convert_kernel<<<(N_ELEMS / 4 + 255) / 256, 256, 0, stream>>>(H, Abf);
    dim3 tgrid(DIM / 64, DIM / 64);
    transpose_kernel<<<tgrid, 256, 0, stream>>>(W1, WT1);
    transpose_kernel<<<tgrid, 256, 0, stream>>>(W2, WT2);
    hipMemsetAsync(cnt, 0, (size_t)N_NODES * 4, stream);
    hist_kernel<<<(N_EDGES + 255) / 256, 256, 0, stream>>>(rows, cnt);
    scan_kernel<<<1, 1024, 0, stream>>>(cnt, rs, cur);
    scatter_kernel<<<(N_EDGES + 255) / 256, 256, 0, stream>>>(rows, cols, vals, cur, scol, sval);

    dim3 ggrid(M_PAD / 128, DIM / 128);
    // layer 1
    mfma_gemm<<<ggrid, 256, 0, stream>>>(Abf, WT1, Xbf, N_NODES);
    spmm1_kernel<<<N_NODES, 128, 0, stream>>>(Xbf, rs, scol, sval, b1, hbf);
    // layer 2
    mfma_gemm<<<ggrid, 256, 0, stream>>>(hbf, WT2, Xbf, N_NODES);
    spmm2_kernel<<<N_NODES, 128, 0, stream>>>(Xbf, rs, scol, sval, b2, out);
}